// Round 3
// baseline (194.026 us; speedup 1.0000x reference)
//
#include <hip/hip_runtime.h>
#include <hip/hip_bf16.h>
#include <stdint.h>

#define D_DIM 1024
#define B_DIM 8
#define S_DIM 1024

typedef __bf16 bf16;
typedef __bf16 bf16x4 __attribute__((ext_vector_type(4)));
typedef __bf16 bf16x8 __attribute__((ext_vector_type(8)));
typedef float floatx4 __attribute__((ext_vector_type(4)));

__device__ __forceinline__ void async_copy16(const void* g, void* l) {
    __builtin_amdgcn_global_load_lds(
        (const __attribute__((address_space(1))) void*)g,
        (__attribute__((address_space(3))) void*)l, 16, 0, 0);
}

// ---------------------------------------------------------------------------
// Prep kernel (fused): blocks [0,4096) cast head/dep fp32->bf16 + W-projection
// (one wave per row); blocks [4096,5120) transpose+cast U -> Ut.
// ---------------------------------------------------------------------------
__global__ __launch_bounds__(256) void prep_kernel(
    const float* __restrict__ head, const float* __restrict__ dep,
    const float* __restrict__ U, const float* __restrict__ edge_W,
    bf16* __restrict__ head_b, bf16* __restrict__ dep_b,
    bf16* __restrict__ Ut,
    float* __restrict__ s_head, float* __restrict__ s_dep)
{
    int blk = blockIdx.x;
    if (blk < 4096) {
        // ---- cast + projection: 4 rows per block, one wave per row ----
        int wid  = threadIdx.x >> 6;
        int lane = threadIdx.x & 63;
        int row  = blk * 4 + wid;

        const float* src;
        bf16* dst;
        const float* w;
        float* sout;
        if (row < B_DIM * S_DIM) {
            src  = head   + (size_t)row * D_DIM;
            dst  = head_b + (size_t)row * D_DIM;
            w    = edge_W;
            sout = s_head + row;
        } else {
            int r = row - B_DIM * S_DIM;
            src  = dep   + (size_t)r * D_DIM;
            dst  = dep_b + (size_t)r * D_DIM;
            w    = edge_W + D_DIM;
            sout = s_dep + r;
        }
        float d = 0.0f;
        #pragma unroll
        for (int it = 0; it < 4; ++it) {
            int idx = it * 64 + lane;
            float4 v  = ((const float4*)src)[idx];
            float4 wv = ((const float4*)w)[idx];
            bf16x4 o;
            o[0] = (bf16)v.x; o[1] = (bf16)v.y; o[2] = (bf16)v.z; o[3] = (bf16)v.w;
            ((bf16x4*)dst)[idx] = o;
            d += v.x * wv.x + v.y * wv.y + v.z * wv.z + v.w * wv.w;
        }
        #pragma unroll
        for (int off = 32; off > 0; off >>= 1)
            d += __shfl_down(d, off, 64);
        if (lane == 0) *sout = d;
    } else {
        // ---- transpose + cast U: 32x32 tile per block ----
        __shared__ float tile[32][33];
        int t  = blk - 4096;
        int bx = (t & 31) * 32;
        int by = (t >> 5) * 32;
        int tx = threadIdx.x & 31;
        int ty4 = (threadIdx.x >> 5) * 4;
        #pragma unroll
        for (int i = 0; i < 4; ++i)
            tile[ty4 + i][tx] = U[(size_t)(by + ty4 + i) * D_DIM + bx + tx];
        __syncthreads();
        #pragma unroll
        for (int i = 0; i < 4; ++i)
            Ut[(size_t)(bx + ty4 + i) * D_DIM + by + tx] = (bf16)tile[tx][ty4 + i];
    }
}

// ---------------------------------------------------------------------------
// GEMM: C[m][n] = sum_k A[m][k] * Bt[n][k], K = 1024.
// 128x128 tile, BK=64, 256 threads (2x2 waves), 16x16x32 bf16 MFMA.
// A: LDS double-buffered via global_load_lds (XOR-swizzled), partial-vmcnt
//    pipeline (A(k+1) staged before waiting A(k); never drain to 0 in-loop).
// B: NO LDS — fragments loaded straight from global into VGPRs (per-lane
//    16B load matches the MFMA B layout exactly); B is ~2 MB -> L2-resident
//    with heavy cross-block reuse. Halves LDS read traffic (the R2
//    bottleneck: 128 KB/CU-iter @ 85 B/cyc vs 310 cyc of MFMA).
// B(k+1) fragments prefetch into registers during compute(k).
// EPI=0: store bf16.  EPI=1: store fp32 + s_row[m] + s_col[n] + bias (nt).
// ---------------------------------------------------------------------------
template <int EPI>
__global__ __launch_bounds__(256, 2) void gemm_bt_kernel(
    const bf16* __restrict__ A, const bf16* __restrict__ Bt,
    void* __restrict__ Cout,
    int N,
    long long sA, long long sB, long long sC,
    const float* __restrict__ s_row, const float* __restrict__ s_col,
    const float* __restrict__ bias)
{
    const int BK = 64;
    const int KITER = D_DIM / BK;          // 16
    __shared__ bf16 As[2][128 * BK];       // 2 x 16 KB

    int tid  = threadIdx.x;
    int wid  = tid >> 6;
    int lane = tid & 63;
    int quad = lane >> 4;
    int l16  = lane & 15;
    int wr   = wid >> 1;
    int wc   = wid & 1;

    int tile_m = blockIdx.y * 128;
    int tile_n = blockIdx.x * 128;
    int bz     = blockIdx.z;

    const bf16* Ab = A  + (size_t)bz * sA + (size_t)tile_m * D_DIM;
    const bf16* Bb = Bt + (size_t)bz * sB + (size_t)tile_n * D_DIM;

    // per-lane B row pointers: row = wc*64 + nt*16 + l16
    const bf16* brow[4];
    #pragma unroll
    for (int nt = 0; nt < 4; ++nt)
        brow[nt] = Bb + (size_t)(wc * 64 + nt * 16 + l16) * D_DIM + quad * 8;

    floatx4 zero = {0.0f, 0.0f, 0.0f, 0.0f};
    floatx4 acc[4][4];
    #pragma unroll
    for (int i = 0; i < 4; ++i)
        #pragma unroll
        for (int j = 0; j < 4; ++j) acc[i][j] = zero;

    // stage A slab (128x64 = 16 KB = 1024 granules; 4 per thread)
    auto stageA = [&](int k0, int buf) {
        #pragma unroll
        for (int it = 0; it < 4; ++it) {
            int g  = wid * 256 + it * 64 + lane;
            int r  = g >> 3;
            int cg = (g & 7) ^ (r & 7);              // XOR swizzle
            int ldsoff = (wid * 256 + it * 64) * 8;  // wave-uniform
            async_copy16(Ab + (size_t)r * D_DIM + k0 + cg * 8, &As[buf][ldsoff]);
        }
    };

    auto loadB = [&](int k0, bf16x8 breg[2][4]) {
        #pragma unroll
        for (int h = 0; h < 2; ++h)
            #pragma unroll
            for (int nt = 0; nt < 4; ++nt)
                breg[h][nt] = *(const bf16x8*)&brow[nt][k0 + h * 32];
    };

    bf16x8 breg[2][2][4];

    stageA(0, 0);                           // queue: A0:4
    asm volatile("" ::: "memory");          // pin VMEM issue order
    loadB(0, breg[0]);                      // queue: A0:4, B0:8
    asm volatile("" ::: "memory");

    #pragma unroll
    for (int k = 0; k < KITER; ++k) {
        int buf = k & 1;
        if (k + 1 < KITER) {
            stageA((k + 1) * BK, buf ^ 1);  // queue: A(k):4, B(k):8, A(k+1):4
            asm volatile("" ::: "memory");
            // drain exactly A(k); prefetches stay in flight
            asm volatile("s_waitcnt vmcnt(12)\n\ts_barrier" ::: "memory");
            loadB((k + 1) * BK, breg[(k + 1) & 1]);
        } else {
            asm volatile("s_waitcnt vmcnt(8)\n\ts_barrier" ::: "memory");
        }

        #pragma unroll
        for (int h = 0; h < 2; ++h) {
            bf16x8 a[4];
            #pragma unroll
            for (int mt = 0; mt < 4; ++mt) {
                int row  = wr * 64 + mt * 16 + l16;
                int slot = (h * 4 + quad) ^ (row & 7);
                a[mt] = *(const bf16x8*)&As[buf][row * BK + slot * 8];
            }
            #pragma unroll
            for (int mt = 0; mt < 4; ++mt)
                #pragma unroll
                for (int nt = 0; nt < 4; ++nt)
                    acc[mt][nt] = __builtin_amdgcn_mfma_f32_16x16x32_bf16(
                        a[mt], breg[k & 1][h][nt], acc[mt][nt], 0, 0, 0);
        }
        // all waves done reading As[buf] before next-iter stage overwrites
        asm volatile("s_barrier" ::: "memory");
    }

    // ---- epilogue: C/D layout col = lane&15, row = quad*4 + reg ----
    int row0 = tile_m + wr * 64;
    int col0 = tile_n + wc * 64;
    if (EPI == 0) {
        bf16* Cb = (bf16*)Cout + (size_t)bz * sC;
        #pragma unroll
        for (int mt = 0; mt < 4; ++mt)
            #pragma unroll
            for (int r = 0; r < 4; ++r) {
                int row = row0 + mt * 16 + quad * 4 + r;
                #pragma unroll
                for (int nt = 0; nt < 4; ++nt) {
                    int col = col0 + nt * 16 + l16;
                    Cb[(size_t)row * N + col] = (bf16)acc[mt][nt][r];
                }
            }
    } else {
        float* Cf = (float*)Cout + (size_t)bz * sC;
        float b0 = bias[0];
        const float* srow = s_row + (size_t)bz * S_DIM;
        const float* scol = s_col + (size_t)bz * S_DIM;
        #pragma unroll
        for (int mt = 0; mt < 4; ++mt)
            #pragma unroll
            for (int r = 0; r < 4; ++r) {
                int row = row0 + mt * 16 + quad * 4 + r;
                float sh = srow[row] + b0;
                #pragma unroll
                for (int nt = 0; nt < 4; ++nt) {
                    int col = col0 + nt * 16 + l16;
                    __builtin_nontemporal_store(acc[mt][nt][r] + sh + scol[col],
                                                &Cf[(size_t)row * N + col]);
                }
            }
    }
}

// ---------------------------------------------------------------------------
extern "C" void kernel_launch(void* const* d_in, const int* in_sizes, int n_in,
                              void* d_out, int out_size, void* d_ws, size_t ws_size,
                              hipStream_t stream) {
    const float* head   = (const float*)d_in[0];
    const float* dep    = (const float*)d_in[1];
    const float* edge_U = (const float*)d_in[2];
    const float* edge_W = (const float*)d_in[3];
    const float* edge_b = (const float*)d_in[4];
    float* out = (float*)d_out;

    char* ws = (char*)d_ws;
    const size_t nBSD = (size_t)B_DIM * S_DIM * D_DIM;

    bf16*  head_b = (bf16*)ws;  ws += nBSD * sizeof(bf16);
    bf16*  dep_b  = (bf16*)ws;  ws += nBSD * sizeof(bf16);
    bf16*  Ut     = (bf16*)ws;  ws += (size_t)D_DIM * D_DIM * sizeof(bf16);
    bf16*  tmp_b  = (bf16*)ws;  ws += nBSD * sizeof(bf16);
    float* s_head = (float*)ws; ws += (size_t)B_DIM * S_DIM * sizeof(float);
    float* s_dep  = (float*)ws; ws += (size_t)B_DIM * S_DIM * sizeof(float);

    // 1. fused cast+projection (4096 blocks) and U-transpose (1024 blocks)
    prep_kernel<<<4096 + 1024, 256, 0, stream>>>(
        head, dep, edge_U, edge_W, head_b, dep_b, Ut, s_head, s_dep);

    // 2. tmp[b,i,k] = head[b,i,:] @ U   ([8192 x 1024] x Ut^T)
    gemm_bt_kernel<0><<<dim3(D_DIM / 128, (B_DIM * S_DIM) / 128, 1), 256, 0, stream>>>(
        head_b, Ut, tmp_b, D_DIM,
        0, 0, 0, nullptr, nullptr, nullptr);

    // 3. out[b,i,j] = tmp[b,i,:] @ dep[b,j,:]^T + s_head + s_dep + bias
    gemm_bt_kernel<1><<<dim3(S_DIM / 128, S_DIM / 128, B_DIM), 256, 0, stream>>>(
        tmp_b, dep_b, out, S_DIM,
        (long long)S_DIM * D_DIM, (long long)S_DIM * D_DIM,
        (long long)S_DIM * S_DIM,
        s_head, s_dep, edge_b);
}

// Round 4
// 163.376 us; speedup vs baseline: 1.1876x; 1.1876x over previous
//
#include <hip/hip_runtime.h>
#include <hip/hip_bf16.h>
#include <stdint.h>

#define D_DIM 1024
#define B_DIM 8
#define S_DIM 1024

typedef __bf16 bf16;
typedef __bf16 bf16x4 __attribute__((ext_vector_type(4)));
typedef __bf16 bf16x8 __attribute__((ext_vector_type(8)));
typedef float floatx4 __attribute__((ext_vector_type(4)));

__device__ __forceinline__ void async_copy16(const void* g, void* l) {
    __builtin_amdgcn_global_load_lds(
        (const __attribute__((address_space(1))) void*)g,
        (__attribute__((address_space(3))) void*)l, 16, 0, 0);
}

// ---------------------------------------------------------------------------
// Prep kernel (fused): blocks [0,4096) cast head/dep fp32->bf16 + W-projection
// (one wave per row); blocks [4096,5120) transpose+cast U -> Ut.
// ---------------------------------------------------------------------------
__global__ __launch_bounds__(256) void prep_kernel(
    const float* __restrict__ head, const float* __restrict__ dep,
    const float* __restrict__ U, const float* __restrict__ edge_W,
    bf16* __restrict__ head_b, bf16* __restrict__ dep_b,
    bf16* __restrict__ Ut,
    float* __restrict__ s_head, float* __restrict__ s_dep)
{
    int blk = blockIdx.x;
    if (blk < 4096) {
        int wid  = threadIdx.x >> 6;
        int lane = threadIdx.x & 63;
        int row  = blk * 4 + wid;

        const float* src;
        bf16* dst;
        const float* w;
        float* sout;
        if (row < B_DIM * S_DIM) {
            src  = head   + (size_t)row * D_DIM;
            dst  = head_b + (size_t)row * D_DIM;
            w    = edge_W;
            sout = s_head + row;
        } else {
            int r = row - B_DIM * S_DIM;
            src  = dep   + (size_t)r * D_DIM;
            dst  = dep_b + (size_t)r * D_DIM;
            w    = edge_W + D_DIM;
            sout = s_dep + r;
        }
        float d = 0.0f;
        #pragma unroll
        for (int it = 0; it < 4; ++it) {
            int idx = it * 64 + lane;
            float4 v  = ((const float4*)src)[idx];
            float4 wv = ((const float4*)w)[idx];
            bf16x4 o;
            o[0] = (bf16)v.x; o[1] = (bf16)v.y; o[2] = (bf16)v.z; o[3] = (bf16)v.w;
            ((bf16x4*)dst)[idx] = o;
            d += v.x * wv.x + v.y * wv.y + v.z * wv.z + v.w * wv.w;
        }
        #pragma unroll
        for (int off = 32; off > 0; off >>= 1)
            d += __shfl_down(d, off, 64);
        if (lane == 0) *sout = d;
    } else {
        __shared__ float tile[32][33];
        int t  = blk - 4096;
        int bx = (t & 31) * 32;
        int by = (t >> 5) * 32;
        int tx = threadIdx.x & 31;
        int ty4 = (threadIdx.x >> 5) * 4;
        #pragma unroll
        for (int i = 0; i < 4; ++i)
            tile[ty4 + i][tx] = U[(size_t)(by + ty4 + i) * D_DIM + bx + tx];
        __syncthreads();
        #pragma unroll
        for (int i = 0; i < 4; ++i)
            Ut[(size_t)(bx + ty4 + i) * D_DIM + by + tx] = (bf16)tile[tx][ty4 + i];
    }
}

// ---------------------------------------------------------------------------
// GEMM: C[m][n] = sum_k A[m][k] * Bt[n][k], K = 1024.
// m97-proven structure: 128x128 tile, BK=64, SINGLE-buffered LDS (32 KB ->
// 3 blocks/CU at __launch_bounds__(256,3) = 12 waves/CU, the measured
// occupancy level where inter-wave overlap hides the barrier drain).
// A and B both staged via global_load_lds width-16, XOR-swizzled granules
// (LDS slot s of row r holds global granule s^(r&7); readers index
// slot = gk^(r&7)) -> conflict-free ds_read_b128.
// EPI=0: store bf16.  EPI=1: fp32 + s_row[m] + s_col[n] + bias, nontemporal.
// ---------------------------------------------------------------------------
template <int EPI>
__global__ __launch_bounds__(256, 3) void gemm_bt_kernel(
    const bf16* __restrict__ A, const bf16* __restrict__ Bt,
    void* __restrict__ Cout,
    int N,
    long long sA, long long sB, long long sC,
    const float* __restrict__ s_row, const float* __restrict__ s_col,
    const float* __restrict__ bias)
{
    const int BK = 64;
    const int KITER = D_DIM / BK;          // 16
    __shared__ bf16 As[128 * BK];          // 16 KB
    __shared__ bf16 Bs[128 * BK];          // 16 KB

    int tid  = threadIdx.x;
    int wid  = tid >> 6;
    int lane = tid & 63;
    int quad = lane >> 4;
    int l16  = lane & 15;
    int wr   = wid >> 1;
    int wc   = wid & 1;

    int tile_m = blockIdx.y * 128;
    int tile_n = blockIdx.x * 128;
    int bz     = blockIdx.z;

    const bf16* Ab = A  + (size_t)bz * sA + (size_t)tile_m * D_DIM;
    const bf16* Bb = Bt + (size_t)bz * sB + (size_t)tile_n * D_DIM;

    floatx4 zero = {0.0f, 0.0f, 0.0f, 0.0f};
    floatx4 acc[4][4];
    #pragma unroll
    for (int i = 0; i < 4; ++i)
        #pragma unroll
        for (int j = 0; j < 4; ++j) acc[i][j] = zero;

    for (int k0 = 0; k0 < D_DIM; k0 += BK) {
        // ---- stage A and B slabs: 1024 granules of 16B each ----
        #pragma unroll
        for (int it = 0; it < 4; ++it) {
            int g  = wid * 256 + it * 64 + lane;
            int r  = g >> 3;
            int cg = (g & 7) ^ (r & 7);              // XOR swizzle
            int ldsoff = (wid * 256 + it * 64) * 8;  // wave-uniform
            async_copy16(Ab + (size_t)r * D_DIM + k0 + cg * 8, &As[ldsoff]);
            async_copy16(Bb + (size_t)r * D_DIM + k0 + cg * 8, &Bs[ldsoff]);
        }
        __syncthreads();   // compiler emits vmcnt(0) drain: staging complete

        #pragma unroll
        for (int kk = 0; kk < BK; kk += 32) {
            bf16x8 a[4], b[4];
            #pragma unroll
            for (int mt = 0; mt < 4; ++mt) {
                int row  = wr * 64 + mt * 16 + l16;
                int slot = ((kk >> 3) + quad) ^ (row & 7);
                a[mt] = *(const bf16x8*)&As[row * BK + slot * 8];
            }
            #pragma unroll
            for (int nt = 0; nt < 4; ++nt) {
                int row  = wc * 64 + nt * 16 + l16;
                int slot = ((kk >> 3) + quad) ^ (row & 7);
                b[nt] = *(const bf16x8*)&Bs[row * BK + slot * 8];
            }
            #pragma unroll
            for (int mt = 0; mt < 4; ++mt)
                #pragma unroll
                for (int nt = 0; nt < 4; ++nt)
                    acc[mt][nt] = __builtin_amdgcn_mfma_f32_16x16x32_bf16(
                        a[mt], b[nt], acc[mt][nt], 0, 0, 0);
        }
        __syncthreads();   // all reads done before next-iter staging
    }

    // ---- epilogue: C/D layout col = lane&15, row = quad*4 + reg ----
    int row0 = tile_m + wr * 64;
    int col0 = tile_n + wc * 64;
    if (EPI == 0) {
        bf16* Cb = (bf16*)Cout + (size_t)bz * sC;
        #pragma unroll
        for (int mt = 0; mt < 4; ++mt)
            #pragma unroll
            for (int r = 0; r < 4; ++r) {
                int row = row0 + mt * 16 + quad * 4 + r;
                #pragma unroll
                for (int nt = 0; nt < 4; ++nt) {
                    int col = col0 + nt * 16 + l16;
                    Cb[(size_t)row * N + col] = (bf16)acc[mt][nt][r];
                }
            }
    } else {
        float* Cf = (float*)Cout + (size_t)bz * sC;
        float b0 = bias[0];
        const float* srow = s_row + (size_t)bz * S_DIM;
        const float* scol = s_col + (size_t)bz * S_DIM;
        #pragma unroll
        for (int mt = 0; mt < 4; ++mt)
            #pragma unroll
            for (int r = 0; r < 4; ++r) {
                int row = row0 + mt * 16 + quad * 4 + r;
                float sh = srow[row] + b0;
                #pragma unroll
                for (int nt = 0; nt < 4; ++nt) {
                    int col = col0 + nt * 16 + l16;
                    __builtin_nontemporal_store(acc[mt][nt][r] + sh + scol[col],
                                                &Cf[(size_t)row * N + col]);
                }
            }
    }
}

// ---------------------------------------------------------------------------
extern "C" void kernel_launch(void* const* d_in, const int* in_sizes, int n_in,
                              void* d_out, int out_size, void* d_ws, size_t ws_size,
                              hipStream_t stream) {
    const float* head   = (const float*)d_in[0];
    const float* dep    = (const float*)d_in[1];
    const float* edge_U = (const float*)d_in[2];
    const float* edge_W = (const float*)d_in[3];
    const float* edge_b = (const float*)d_in[4];
    float* out = (float*)d_out;

    char* ws = (char*)d_ws;
    const size_t nBSD = (size_t)B_DIM * S_DIM * D_DIM;

    bf16*  head_b = (bf16*)ws;  ws += nBSD * sizeof(bf16);
    bf16*  dep_b  = (bf16*)ws;  ws += nBSD * sizeof(bf16);
    bf16*  Ut     = (bf16*)ws;  ws += (size_t)D_DIM * D_DIM * sizeof(bf16);
    bf16*  tmp_b  = (bf16*)ws;  ws += nBSD * sizeof(bf16);
    float* s_head = (float*)ws; ws += (size_t)B_DIM * S_DIM * sizeof(float);
    float* s_dep  = (float*)ws; ws += (size_t)B_DIM * S_DIM * sizeof(float);

    // 1. fused cast+projection (4096 blocks) and U-transpose (1024 blocks)
    prep_kernel<<<4096 + 1024, 256, 0, stream>>>(
        head, dep, edge_U, edge_W, head_b, dep_b, Ut, s_head, s_dep);

    // 2. tmp[b,i,k] = head[b,i,:] @ U   ([8192 x 1024] x Ut^T)
    gemm_bt_kernel<0><<<dim3(D_DIM / 128, (B_DIM * S_DIM) / 128, 1), 256, 0, stream>>>(
        head_b, Ut, tmp_b, D_DIM,
        0, 0, 0, nullptr, nullptr, nullptr);

    // 3. out[b,i,j] = tmp[b,i,:] @ dep[b,j,:]^T + s_head + s_dep + bias
    gemm_bt_kernel<1><<<dim3(S_DIM / 128, S_DIM / 128, B_DIM), 256, 0, stream>>>(
        tmp_b, dep_b, out, S_DIM,
        (long long)S_DIM * D_DIM, (long long)S_DIM * D_DIM,
        (long long)S_DIM * S_DIM,
        s_head, s_dep, edge_b);
}

// Round 5
// 163.046 us; speedup vs baseline: 1.1900x; 1.0020x over previous
//
#include <hip/hip_runtime.h>
#include <hip/hip_bf16.h>
#include <stdint.h>

#define D_DIM 1024
#define B_DIM 8
#define S_DIM 1024

typedef __bf16 bf16;
typedef __bf16 bf16x4 __attribute__((ext_vector_type(4)));
typedef __bf16 bf16x8 __attribute__((ext_vector_type(8)));
typedef float floatx4 __attribute__((ext_vector_type(4)));

__device__ __forceinline__ void async_copy16(const void* g, void* l) {
    __builtin_amdgcn_global_load_lds(
        (const __attribute__((address_space(1))) void*)g,
        (__attribute__((address_space(3))) void*)l, 16, 0, 0);
}

// ---------------------------------------------------------------------------
// Prep kernel (fused): blocks [0,4096) cast head/dep fp32->bf16 + W-projection
// (one wave per row); blocks [4096,5120) transpose+cast U -> Ut.
// ---------------------------------------------------------------------------
__global__ __launch_bounds__(256) void prep_kernel(
    const float* __restrict__ head, const float* __restrict__ dep,
    const float* __restrict__ U, const float* __restrict__ edge_W,
    bf16* __restrict__ head_b, bf16* __restrict__ dep_b,
    bf16* __restrict__ Ut,
    float* __restrict__ s_head, float* __restrict__ s_dep)
{
    int blk = blockIdx.x;
    if (blk < 4096) {
        int wid  = threadIdx.x >> 6;
        int lane = threadIdx.x & 63;
        int row  = blk * 4 + wid;

        const float* src;
        bf16* dst;
        const float* w;
        float* sout;
        if (row < B_DIM * S_DIM) {
            src  = head   + (size_t)row * D_DIM;
            dst  = head_b + (size_t)row * D_DIM;
            w    = edge_W;
            sout = s_head + row;
        } else {
            int r = row - B_DIM * S_DIM;
            src  = dep   + (size_t)r * D_DIM;
            dst  = dep_b + (size_t)r * D_DIM;
            w    = edge_W + D_DIM;
            sout = s_dep + r;
        }
        float d = 0.0f;
        #pragma unroll
        for (int it = 0; it < 4; ++it) {
            int idx = it * 64 + lane;
            float4 v  = ((const float4*)src)[idx];
            float4 wv = ((const float4*)w)[idx];
            bf16x4 o;
            o[0] = (bf16)v.x; o[1] = (bf16)v.y; o[2] = (bf16)v.z; o[3] = (bf16)v.w;
            ((bf16x4*)dst)[idx] = o;
            d += v.x * wv.x + v.y * wv.y + v.z * wv.z + v.w * wv.w;
        }
        #pragma unroll
        for (int off = 32; off > 0; off >>= 1)
            d += __shfl_down(d, off, 64);
        if (lane == 0) *sout = d;
    } else {
        __shared__ float tile[32][33];
        int t  = blk - 4096;
        int bx = (t & 31) * 32;
        int by = (t >> 5) * 32;
        int tx = threadIdx.x & 31;
        int ty4 = (threadIdx.x >> 5) * 4;
        #pragma unroll
        for (int i = 0; i < 4; ++i)
            tile[ty4 + i][tx] = U[(size_t)(by + ty4 + i) * D_DIM + bx + tx];
        __syncthreads();
        #pragma unroll
        for (int i = 0; i < 4; ++i)
            Ut[(size_t)(bx + ty4 + i) * D_DIM + by + tx] = (bf16)tile[tx][ty4 + i];
    }
}

// ---------------------------------------------------------------------------
// GEMM: C[m][n] = sum_k A[m][k] * Bt[n][k], K = 1024.
// 128x128 tile, BK=64, *512 threads* (8 waves in 2x4): with the fixed
// 512-block grids this gives 2 blocks x 8 waves = 16 waves/CU (vs 8 at
// 256-thread blocks — the R2/R4 plateau was grid-limited occupancy).
// Single-buffered m97 K-loop (32 KB LDS/block); global_load_lds width-16;
// XOR-swizzled granules -> conflict-free ds_read_b128.
// Per wave: 64x32 output = acc[4][2], 16 MFMA + 12 ds_read_b128 per slab.
// EPI=0: store bf16.  EPI=1: fp32 + s_row[m] + s_col[n] + bias, nontemporal.
// ---------------------------------------------------------------------------
template <int EPI>
__global__ __launch_bounds__(512, 4) void gemm_bt_kernel(
    const bf16* __restrict__ A, const bf16* __restrict__ Bt,
    void* __restrict__ Cout,
    int N,
    long long sA, long long sB, long long sC,
    const float* __restrict__ s_row, const float* __restrict__ s_col,
    const float* __restrict__ bias)
{
    const int BK = 64;
    __shared__ bf16 As[128 * BK];          // 16 KB
    __shared__ bf16 Bs[128 * BK];          // 16 KB

    int tid  = threadIdx.x;
    int wid  = tid >> 6;       // 0..7
    int lane = tid & 63;
    int quad = lane >> 4;
    int l16  = lane & 15;
    int wr   = wid >> 2;       // 0..1 -> 64-row strip
    int wc   = wid & 3;        // 0..3 -> 32-col strip

    int tile_m = blockIdx.y * 128;
    int tile_n = blockIdx.x * 128;
    int bz     = blockIdx.z;

    const bf16* Ab = A  + (size_t)bz * sA + (size_t)tile_m * D_DIM;
    const bf16* Bb = Bt + (size_t)bz * sB + (size_t)tile_n * D_DIM;

    floatx4 zero = {0.0f, 0.0f, 0.0f, 0.0f};
    floatx4 acc[4][2];
    #pragma unroll
    for (int i = 0; i < 4; ++i)
        #pragma unroll
        for (int j = 0; j < 2; ++j) acc[i][j] = zero;

    for (int k0 = 0; k0 < D_DIM; k0 += BK) {
        // ---- stage A and B slabs: 1024 granules each, 2 per thread ----
        #pragma unroll
        for (int it = 0; it < 2; ++it) {
            int g  = wid * 128 + it * 64 + lane;
            int r  = g >> 3;
            int cg = (g & 7) ^ (r & 7);              // XOR swizzle
            int ldsoff = (wid * 128 + it * 64) * 8;  // wave-uniform
            async_copy16(Ab + (size_t)r * D_DIM + k0 + cg * 8, &As[ldsoff]);
            async_copy16(Bb + (size_t)r * D_DIM + k0 + cg * 8, &Bs[ldsoff]);
        }
        __syncthreads();   // vmcnt(0) drain: staging complete

        #pragma unroll
        for (int kk = 0; kk < BK; kk += 32) {
            bf16x8 a[4], b[2];
            #pragma unroll
            for (int mt = 0; mt < 4; ++mt) {
                int row  = wr * 64 + mt * 16 + l16;
                int slot = ((kk >> 3) + quad) ^ (row & 7);
                a[mt] = *(const bf16x8*)&As[row * BK + slot * 8];
            }
            #pragma unroll
            for (int nt = 0; nt < 2; ++nt) {
                int row  = wc * 32 + nt * 16 + l16;
                int slot = ((kk >> 3) + quad) ^ (row & 7);
                b[nt] = *(const bf16x8*)&Bs[row * BK + slot * 8];
            }
            #pragma unroll
            for (int mt = 0; mt < 4; ++mt)
                #pragma unroll
                for (int nt = 0; nt < 2; ++nt)
                    acc[mt][nt] = __builtin_amdgcn_mfma_f32_16x16x32_bf16(
                        a[mt], b[nt], acc[mt][nt], 0, 0, 0);
        }
        __syncthreads();   // all reads done before next-iter staging
    }

    // ---- epilogue: C/D layout col = lane&15, row = quad*4 + reg ----
    int row0 = tile_m + wr * 64;
    int col0 = tile_n + wc * 32;
    if (EPI == 0) {
        bf16* Cb = (bf16*)Cout + (size_t)bz * sC;
        #pragma unroll
        for (int mt = 0; mt < 4; ++mt)
            #pragma unroll
            for (int r = 0; r < 4; ++r) {
                int row = row0 + mt * 16 + quad * 4 + r;
                #pragma unroll
                for (int nt = 0; nt < 2; ++nt) {
                    int col = col0 + nt * 16 + l16;
                    Cb[(size_t)row * N + col] = (bf16)acc[mt][nt][r];
                }
            }
    } else {
        float* Cf = (float*)Cout + (size_t)bz * sC;
        float b0 = bias[0];
        const float* srow = s_row + (size_t)bz * S_DIM;
        const float* scol = s_col + (size_t)bz * S_DIM;
        #pragma unroll
        for (int mt = 0; mt < 4; ++mt)
            #pragma unroll
            for (int r = 0; r < 4; ++r) {
                int row = row0 + mt * 16 + quad * 4 + r;
                float sh = srow[row] + b0;
                #pragma unroll
                for (int nt = 0; nt < 2; ++nt) {
                    int col = col0 + nt * 16 + l16;
                    __builtin_nontemporal_store(acc[mt][nt][r] + sh + scol[col],
                                                &Cf[(size_t)row * N + col]);
                }
            }
    }
}

// ---------------------------------------------------------------------------
extern "C" void kernel_launch(void* const* d_in, const int* in_sizes, int n_in,
                              void* d_out, int out_size, void* d_ws, size_t ws_size,
                              hipStream_t stream) {
    const float* head   = (const float*)d_in[0];
    const float* dep    = (const float*)d_in[1];
    const float* edge_U = (const float*)d_in[2];
    const float* edge_W = (const float*)d_in[3];
    const float* edge_b = (const float*)d_in[4];
    float* out = (float*)d_out;

    char* ws = (char*)d_ws;
    const size_t nBSD = (size_t)B_DIM * S_DIM * D_DIM;

    bf16*  head_b = (bf16*)ws;  ws += nBSD * sizeof(bf16);
    bf16*  dep_b  = (bf16*)ws;  ws += nBSD * sizeof(bf16);
    bf16*  Ut     = (bf16*)ws;  ws += (size_t)D_DIM * D_DIM * sizeof(bf16);
    bf16*  tmp_b  = (bf16*)ws;  ws += nBSD * sizeof(bf16);
    float* s_head = (float*)ws; ws += (size_t)B_DIM * S_DIM * sizeof(float);
    float* s_dep  = (float*)ws; ws += (size_t)B_DIM * S_DIM * sizeof(float);

    // 1. fused cast+projection (4096 blocks) and U-transpose (1024 blocks)
    prep_kernel<<<4096 + 1024, 256, 0, stream>>>(
        head, dep, edge_U, edge_W, head_b, dep_b, Ut, s_head, s_dep);

    // 2. tmp[b,i,k] = head[b,i,:] @ U   ([8192 x 1024] x Ut^T)
    gemm_bt_kernel<0><<<dim3(D_DIM / 128, (B_DIM * S_DIM) / 128, 1), 512, 0, stream>>>(
        head_b, Ut, tmp_b, D_DIM,
        0, 0, 0, nullptr, nullptr, nullptr);

    // 3. out[b,i,j] = tmp[b,i,:] @ dep[b,j,:]^T + s_head + s_dep + bias
    gemm_bt_kernel<1><<<dim3(S_DIM / 128, S_DIM / 128, B_DIM), 512, 0, stream>>>(
        tmp_b, dep_b, out, S_DIM,
        (long long)S_DIM * D_DIM, (long long)S_DIM * D_DIM,
        (long long)S_DIM * S_DIM,
        s_head, s_dep, edge_b);
}